// Round 9
// baseline (218.153 us; speedup 1.0000x reference)
//
#include <hip/hip_runtime.h>
#include <stdint.h>

typedef unsigned long long u64;

#define CHUNK 128
#define WARM  128
#define SLEN  (WARM + CHUNK)        // 256 steps per chunk, lockstep
#define CPW   8                     // chunks per wave
#define WIN   (CPW * CHUNK + WARM)  // 1152-elem staged window
#define PD    4
#define NB    8192
#define LOG2PI_F 1.8378770664093453f

// ---------------- bucket histogram (LDS-local, grid-stride, 64 blocks) -------
__device__ __forceinline__ int bucket_of(float tv, float scale) {
    int b = (int)(tv * scale);
    return b > (NB - 1) ? (NB - 1) : (b < 0 ? 0 : b);
}

__global__ __launch_bounds__(256) void hist_k(const float4* __restrict__ t4,
                                              unsigned* __restrict__ hist,
                                              float scale, int n4) {
    __shared__ unsigned lh[NB];
    for (int v = threadIdx.x; v < NB; v += 256) lh[v] = 0u;
    __syncthreads();
    for (int i = blockIdx.x * 256 + threadIdx.x; i < n4; i += gridDim.x * 256) {
        float4 tv = t4[i];
        atomicAdd(&lh[bucket_of(tv.x, scale)], 1u);
        atomicAdd(&lh[bucket_of(tv.y, scale)], 1u);
        atomicAdd(&lh[bucket_of(tv.z, scale)], 1u);
        atomicAdd(&lh[bucket_of(tv.w, scale)], 1u);
    }
    __syncthreads();
    for (int v = threadIdx.x; v < NB; v += 256) {
        unsigned c = lh[v];
        if (c) atomicAdd(&hist[v], c);
    }
}

// ---------------- exclusive scan of 8192 counts (1 block, 1024 thr) ---------
__global__ __launch_bounds__(1024) void scan_k(const unsigned* __restrict__ hist,
                                               unsigned* __restrict__ off,
                                               unsigned* __restrict__ cnt2) {
    __shared__ unsigned ls[1024];
    int tid = threadIdx.x;
    unsigned h[8], tsum = 0;
#pragma unroll
    for (int k = 0; k < 8; ++k) { h[k] = hist[8 * tid + k]; tsum += h[k]; }
    ls[tid] = tsum;
    __syncthreads();
    for (int d = 1; d < 1024; d <<= 1) {
        unsigned yv = (tid >= d) ? ls[tid - d] : 0u;
        __syncthreads();
        ls[tid] += yv;
        __syncthreads();
    }
    unsigned base = ls[tid] - tsum;
#pragma unroll
    for (int k = 0; k < 8; ++k) {
        off[8 * tid + k] = base; cnt2[8 * tid + k] = base; base += h[k];
    }
    if (tid == 1023) off[NB] = base;
}

// ------- scatter keys only, 8 elems/thread, atomics batched ------------------
// key = tbits<<32 | origidx. Final order fixed by bitonic sort -> atomic
// placement order is irrelevant to the result (deterministic output).
__global__ __launch_bounds__(256) void scatter_k(const float4* __restrict__ t4,
                                                 unsigned* __restrict__ cnt2,
                                                 u64* __restrict__ keys,
                                                 float scale, int n8) {
    int i = blockIdx.x * blockDim.x + threadIdx.x;
    if (i >= n8) return;
    float4 a = t4[2 * i], b = t4[2 * i + 1];
    float tv[8] = {a.x, a.y, a.z, a.w, b.x, b.y, b.z, b.w};
    u64 kk[8];
    unsigned pos[8];
#pragma unroll
    for (int k = 0; k < 8; ++k) {
        unsigned bits = __float_as_uint(tv[k]);
        unsigned mk = (bits & 0x80000000u) ? ~bits : (bits | 0x80000000u);
        kk[k] = ((u64)mk << 32) | (u64)(unsigned)(8 * i + k);
        pos[k] = atomicAdd(&cnt2[bucket_of(tv[k], scale)], 1u);
    }
#pragma unroll
    for (int k = 0; k < 8; ++k) keys[pos[k]] = kk[k];
}

__device__ __forceinline__ float decode_key(unsigned h) {
    unsigned b = (h & 0x80000000u) ? (h ^ 0x80000000u) : ~h;
    return __uint_as_float(b);
}

// ------- per-bucket 256-key LDS bitonic sort -> planar tS (float) + idxS -----
__global__ __launch_bounds__(128) void bucket_sort(const u64* __restrict__ keys,
                                                   const unsigned* __restrict__ off,
                                                   float* __restrict__ tS,
                                                   unsigned* __restrict__ idxS) {
    __shared__ u64 sk[256];
    const int b = blockIdx.x;
    const unsigned o = off[b];
    unsigned cnt = off[b + 1] - o; if (cnt > 256u) cnt = 256u;
    const int tid = threadIdx.x;
    for (int v = tid; v < 256; v += 128)
        sk[v] = (v < (int)cnt) ? keys[o + v] : ~0ull;
    __syncthreads();
    for (int k = 2; k <= 256; k <<= 1) {
        for (int j = k >> 1; j >= 1; j >>= 1) {
            int i = ((tid & ~(j - 1)) << 1) | (tid & (j - 1));
            int p = i | j;
            bool up = ((i & k) == 0);
            u64 a = sk[i], bb = sk[p];
            if ((a > bb) == up) { sk[i] = bb; sk[p] = a; }
            __syncthreads();
        }
    }
    for (int v = tid; v < (int)cnt; v += 128) {
        u64 kk = sk[v];
        tS[o + v] = decode_key((unsigned)(kk >> 32));
        idxS[o + v] = (unsigned)kk;
    }
}

// ------- payload gather, one source array per pass (4MB = L2-resident) -------
__global__ __launch_bounds__(256) void gather_pay(const uint4* __restrict__ idx4,
                                                  const float* __restrict__ src,
                                                  float* __restrict__ dst,
                                                  int squared, int n4) {
    int i = blockIdx.x * 256 + threadIdx.x;
    if (i >= n4) return;
    uint4 ix = idx4[i];
    float4 o;
    o.x = src[ix.x]; o.y = src[ix.y]; o.z = src[ix.z]; o.w = src[ix.w];
    if (squared) { o.x *= o.x; o.y *= o.y; o.z *= o.z; o.w *= o.w; }
    ((float4*)dst)[i] = o;
}

// ---------------- DPP helpers (all perms confined to 8-lane groups) ----------
#define DPPMOV(x, ctrl) __int_as_float(__builtin_amdgcn_update_dpp( \
        0, __float_as_int(x), (ctrl), 0xF, 0xF, true))
#define GSUM8(s, x) { s = (x) + DPPMOV((x), 0xB1); s += DPPMOV(s, 0x4E); s += DPPMOV(s, 0x141); }
// allgather: v[k] = value of lane (l^k) within the 8-lane group
#define GATHER8(v, x) { \
    v[0] = (x); v[1] = DPPMOV((x), 0xB1); v[2] = DPPMOV((x), 0x4E); \
    v[3] = DPPMOV(v[1], 0x4E); v[7] = DPPMOV((x), 0x141); \
    v[6] = DPPMOV(v[1], 0x141); v[5] = DPPMOV(v[2], 0x141); v[4] = DPPMOV(v[3], 0x141); }

// ---------------- Kalman: 8 chunks/wave, 8 lanes/chunk, row-per-lane ---------
// lane = g*8 + l: group g handles chunk bi*8+g; lane holds row l of P,
// xor-indexed: P[k] = P[l][l^k]  (diag is k==0 for every lane).
// Staging: coalesced planar reads (tS, ysA, dgA).
// Fake prefix entries (chunk 0 warm): dt=0, d=+inf -> K=0, exact no-op.
__global__ __launch_bounds__(64) void kalman8(
    const float* __restrict__ tS, const float* __restrict__ ysA,
    const float* __restrict__ dgA, const float* __restrict__ lkp,
    float* __restrict__ llp) {
    __shared__ float sst[WIN + 1];
    __shared__ float ssy[WIN];
    __shared__ float ssd[WIN];
    const int lane = threadIdx.x & 63;
    const int g = lane >> 3, l = lane & 7;
    const int bi = blockIdx.x;
    const long base = (long)bi * (CPW * CHUNK) - WARM;

    const float INF = __builtin_huge_valf();
    const float t0 = tS[0];
    for (int p = lane; p < WIN; p += 64) {
        long gi = base + p;
        float tv, yv, dv;
        if (gi >= 0) { tv = tS[gi]; yv = ysA[gi]; dv = dgA[gi]; }
        else { tv = t0; yv = 0.0f; dv = INF; }
        sst[p + 1] = tv; ssy[p] = yv; ssd[p] = dv;
    }
    if (lane == 0) sst[0] = (base >= 1) ? tS[base - 1] : t0;
    __syncthreads();

    const float L2E = 1.44269504088896340736f;
    const float LN2 = 0.6931471805599453f;
    const float c_own = -L2E * __expf(-lkp[2 * l]);
    const float Pinf  = __expf(2.0f * lkp[2 * l + 1]);

    float P[8];
    P[0] = Pinf;
#pragma unroll
    for (int k = 1; k < 8; ++k) P[k] = 0.0f;
    float m = 0.0f, llog = 0.0f, lvw = 0.0f;
    float stp = sst[g * CHUNK];

#define KSTEP(LS, SCORED) { \
    const int p_ = g * CHUNK + (LS); \
    float stn = sst[p_ + 1], yc = ssy[p_], dc = ssd[p_]; \
    float dtc = stn - stp; stp = stn; \
    float phi = __builtin_amdgcn_exp2f(dtc * c_own); \
    float fv[8]; GATHER8(fv, phi) \
    float q0 = phi * phi; \
    float dadd = fmaf(-q0, Pinf, Pinf); \
    float Pp[8]; \
    Pp[0] = fmaf(q0, P[0], dadd); \
    _Pragma("unroll") \
    for (int k = 1; k < 8; ++k) Pp[k] = (phi * fv[k]) * P[k]; \
    float Ph = ((Pp[0] + Pp[1]) + (Pp[2] + Pp[3])) + ((Pp[4] + Pp[5]) + (Pp[6] + Pp[7])); \
    float mp = phi * m; \
    float Ss; GSUM8(Ss, Ph) \
    float ms; GSUM8(ms, mp) \
    float S = Ss + dc; \
    float v = yc - ms; \
    float invS = __builtin_amdgcn_rcpf(S); \
    float w = v * invS; \
    float K = Ph * invS; \
    float pv[8]; GATHER8(pv, Ph) \
    _Pragma("unroll") \
    for (int k = 0; k < 8; ++k) P[k] = fmaf(-K, pv[k], Pp[k]); \
    m = fmaf(Ph, w, mp); \
    if (SCORED) { llog += __builtin_amdgcn_logf(S); lvw = fmaf(v, w, lvw); } }

    for (int ls = 0; ls < WARM; ls += PD) {
#pragma unroll
        for (int u = 0; u < PD; ++u) KSTEP(ls + u, false)
    }
    for (int ls = WARM; ls < SLEN; ls += PD) {
#pragma unroll
        for (int u = 0; u < PD; ++u) KSTEP(ls + u, true)
    }
#undef KSTEP

    if (l == 0)
        llp[bi * CPW + g] = -0.5f * (CHUNK * LOG2PI_F + LN2 * llog + lvw);
}

// ---------------- deterministic final reduction ------------------------------
__global__ __launch_bounds__(256) void reduce_ll(const float* __restrict__ llp,
                                                 float* __restrict__ out, int g) {
    __shared__ float sred[4];
    int tid = threadIdx.x;
    float s = 0.0f;
    for (int i = tid; i < g; i += 256) s += llp[i];
    for (int m = 1; m < 64; m <<= 1) s += __shfl_xor(s, m);
    if ((tid & 63) == 0) sred[tid >> 6] = s;
    __syncthreads();
    if (tid == 0) out[0] = sred[0] + sred[1] + sred[2] + sred[3];
}

extern "C" void kernel_launch(void* const* d_in, const int* in_sizes, int n_in,
                              void* d_out, int out_size, void* d_ws, size_t ws_size,
                              hipStream_t stream) {
    const float* t    = (const float*)d_in[0];
    const float* y    = (const float*)d_in[1];
    const float* yerr = (const float*)d_in[2];
    const float* lkp  = (const float*)d_in[3];
    float* out = (float*)d_out;
    const int n = in_sizes[0];  // 1048576 = 2^20

    // layout: keys [0,8n) -> dead after bucket_sort, reused by ysA/dgA
    u64*      keys = (u64*)d_ws;
    float*    ysA  = (float*)d_ws;                               // [0, 4n)
    float*    dgA  = (float*)((char*)d_ws + (size_t)n * 4);      // [4n, 8n)
    float*    tS   = (float*)((char*)d_ws + (size_t)n * 8);      // [8n, 12n)
    unsigned* idxS = (unsigned*)((char*)d_ws + (size_t)n * 12);  // [12n, 16n)
    float*    llp  = (float*)((char*)d_ws + (size_t)n * 16);     // 8192 floats
    unsigned* hist = (unsigned*)((char*)d_ws + (size_t)n * 16 + 65536);
    unsigned* off  = hist + NB;        // NB+1
    unsigned* cnt2 = off + NB + 64;

    const float scale = (float)NB / ((float)n / 10.0f);
    const int n4 = n / 4;              // 262144
    const int n8 = n / 8;              // 131072

    (void)hipMemsetAsync(hist, 0, NB * sizeof(unsigned), stream);
    hist_k<<<64, 256, 0, stream>>>((const float4*)t, hist, scale, n4);
    scan_k<<<1, 1024, 0, stream>>>(hist, off, cnt2);
    scatter_k<<<(n8 + 255) / 256, 256, 0, stream>>>((const float4*)t, cnt2, keys, scale, n8);
    bucket_sort<<<NB, 128, 0, stream>>>(keys, off, tS, idxS);
    gather_pay<<<(n4 + 255) / 256, 256, 0, stream>>>((const uint4*)idxS, y, ysA, 0, n4);
    gather_pay<<<(n4 + 255) / 256, 256, 0, stream>>>((const uint4*)idxS, yerr, dgA, 1, n4);

    const int G = n / CHUNK;             // 8192 chunks
    kalman8<<<G / CPW, 64, 0, stream>>>(tS, ysA, dgA, lkp, llp);
    reduce_ll<<<1, 256, 0, stream>>>(llp, out, G);
}